// Round 7
// baseline (277.949 us; speedup 1.0000x reference)
//
#include <hip/hip_runtime.h>
#include <hip/hip_fp16.h>

#define DD 40
#define SCAN_B 1024
#define PITER 32   // edges per thread in pass A (chunk = 256*PITER = 8192)
#define NBPB 96    // blocks per partition in pass B kernels

// ---------- Pass A: bin edges by dst-partition (8 bins), packed (local<<17)|src ----------
// One LDS histogram + one global atomicAdd per bin per block reserves a dense window;
// scatter writes fill whole lines -> ~1x writeback.
__global__ void k_binA(const int* __restrict__ src, const int* __restrict__ dst,
                       int* __restrict__ gcur, unsigned* __restrict__ ebin,
                       int E, int PS, unsigned M, int CAP) {
  __shared__ int hist[8];
  __shared__ int curs[8];
  const int tid = threadIdx.x;
  if (tid < 8) hist[tid] = 0;
  __syncthreads();
  const int base = blockIdx.x * (256 * PITER);
  for (int it = 0; it < PITER; ++it) {
    int i = base + it * 256 + tid;
    if (i < E) {
      unsigned t = (unsigned)dst[i];
      int b = (int)(((unsigned long long)t * M) >> 31);
      atomicAdd(&hist[b], 1);
    }
  }
  __syncthreads();
  if (tid < 8) {
    int old = atomicAdd(&gcur[tid], hist[tid]);
    curs[tid] = tid * CAP + old;
  }
  __syncthreads();
  for (int it = 0; it < PITER; ++it) {
    int i = base + it * 256 + tid;
    if (i < E) {
      unsigned t = (unsigned)dst[i];
      int b = (int)(((unsigned long long)t * M) >> 31);
      unsigned local = t - (unsigned)(b * PS);
      int pos = atomicAdd(&curs[b], 1);
      ebin[pos] = (local << 17) | (unsigned)src[i];
    }
  }
}

// ---------- Pass B count: per-partition degree count, all traffic XCD-L2-local ----------
__global__ void k_countB(const unsigned* __restrict__ ebin, const int* __restrict__ gcur,
                         int* __restrict__ ideg, int PS, int CAP) {
  const int p = blockIdx.x & 7;
  const int sub = blockIdx.x >> 3;
  const int start = p * CAP;
  const int end = start + gcur[p];
  for (int i = start + sub * 256 + threadIdx.x; i < end; i += NBPB * 256)
    atomicAdd(&ideg[p * PS + (ebin[i] >> 17)], 1);
}

// ---------- Pass B sort: counting sort within partition (L2-local cursor + es) ----------
__global__ void k_sortB(const unsigned* __restrict__ ebin, const int* __restrict__ gcur,
                        int* __restrict__ cursor, int* __restrict__ es, int PS, int CAP) {
  const int p = blockIdx.x & 7;
  const int sub = blockIdx.x >> 3;
  const int start = p * CAP;
  const int end = start + gcur[p];
  for (int i = start + sub * 256 + threadIdx.x; i < end; i += NBPB * 256) {
    unsigned pk = ebin[i];
    int pos = atomicAdd(&cursor[p * PS + (pk >> 17)], 1);
    es[pos] = (int)(pk & 0x1FFFFu);
  }
}

// dinv[i] = rsqrt(deg+1); xs = fp16(dinv*x) (80B rows)
__global__ void k_prescale(const float4* __restrict__ x4, const int* __restrict__ ideg,
                           float* __restrict__ dinv, uint2* __restrict__ xs8,
                           int n4, int n) {
  int i = blockIdx.x * blockDim.x + threadIdx.x;
  if (i < n) dinv[i] = rsqrtf((float)(ideg[i] + 1));
  if (i < n4) {
    float w = rsqrtf((float)(ideg[i / 10] + 1));
    float4 v = x4[i];
    __half2 ha = __float22half2_rn(make_float2(v.x * w, v.y * w));
    __half2 hb = __float22half2_rn(make_float2(v.z * w, v.w * w));
    uint2 u;
    u.x = *(unsigned*)&ha;
    u.y = *(unsigned*)&hb;
    xs8[i] = u;
  }
}

__global__ void k_scan1(const int* __restrict__ ideg, int* __restrict__ cursor,
                        int* __restrict__ bsum, int n) {
  __shared__ int buf[2][SCAN_B];
  int t = threadIdx.x;
  int gid = blockIdx.x * SCAN_B + t;
  int v = (gid < n) ? ideg[gid] : 0;
  buf[0][t] = v;
  __syncthreads();
  int pi = 0;
  for (int off = 1; off < SCAN_B; off <<= 1) {
    int x = buf[pi][t];
    if (t >= off) x += buf[pi][t - off];
    buf[pi ^ 1][t] = x;
    __syncthreads();
    pi ^= 1;
  }
  if (gid < n) cursor[gid] = buf[pi][t] - v;
  if (t == SCAN_B - 1) bsum[blockIdx.x] = buf[pi][t];
}

__global__ void k_scan2(int* __restrict__ bsum, int nb) {
  __shared__ int buf[2][SCAN_B];
  int t = threadIdx.x;
  int v = (t < nb) ? bsum[t] : 0;
  buf[0][t] = v;
  __syncthreads();
  int pi = 0;
  for (int off = 1; off < SCAN_B; off <<= 1) {
    int x = buf[pi][t];
    if (t >= off) x += buf[pi][t - off];
    buf[pi ^ 1][t] = x;
    __syncthreads();
    pi ^= 1;
  }
  if (t < nb) bsum[t] = buf[pi][t] - v;
}

__global__ void k_scan3(int* __restrict__ cursor, const int* __restrict__ bsum, int n) {
  int gid = blockIdx.x * blockDim.x + threadIdx.x;
  if (gid < n) cursor[gid] += bsum[gid >> 10];
}

// ---------- Gather + fused linear. 12 nodes/wave, 5 lanes x uint4(8 fp16)/node,
// 4-way unroll -> 48 gathers in flight per wave. ----------
template <int OUT_HALF>
__global__ __launch_bounds__(256) void k_layer(
    const uint4* __restrict__ in4, const int* __restrict__ es,
    const int* __restrict__ ideg, const int* __restrict__ cursor,
    const float* __restrict__ dinv, const float* __restrict__ W,
    const float* __restrict__ bias, float* __restrict__ outf,
    __half2* __restrict__ outh, int n) {
  __shared__ float sWT[DD * DD];  // sWT[k*40+j] = W[j*40+k]
  __shared__ float sb[DD];
  __shared__ float srow[48][DD];
  const int tid = threadIdx.x;
  for (int t = tid; t < DD * DD; t += 256) sWT[(t % DD) * DD + t / DD] = W[t];
  if (tid < DD) sb[tid] = bias[tid];

  const int w = tid >> 6, lane = tid & 63;
  const int g = lane / 5, pos = lane - g * 5;  // g==12 (lanes 60-63) idle
  const int v = blockIdx.x * 48 + w * 12 + g;

#define ACC8(U, A)                                   \
  {                                                  \
    const __half2* hh = (const __half2*)&(U);        \
    float2 f0 = __half22float2(hh[0]);               \
    float2 f1 = __half22float2(hh[1]);               \
    float2 f2 = __half22float2(hh[2]);               \
    float2 f3 = __half22float2(hh[3]);               \
    A[0] += f0.x; A[1] += f0.y; A[2] += f1.x;        \
    A[3] += f1.y; A[4] += f2.x; A[5] += f2.y;        \
    A[6] += f3.x; A[7] += f3.y;                      \
  }

  if (g < 12 && v < n) {
    const int e1 = cursor[v];  // end of bucket v (cursor advanced by sortB)
    int e = e1 - ideg[v];      // start
    float a[8], b[8], c[8], d[8];
    {
      uint4 u = in4[(size_t)v * 5 + pos];  // self-loop term
      const __half2* hh = (const __half2*)&u;
      float2 f0 = __half22float2(hh[0]);
      float2 f1 = __half22float2(hh[1]);
      float2 f2 = __half22float2(hh[2]);
      float2 f3 = __half22float2(hh[3]);
      a[0] = f0.x; a[1] = f0.y; a[2] = f1.x; a[3] = f1.y;
      a[4] = f2.x; a[5] = f2.y; a[6] = f3.x; a[7] = f3.y;
#pragma unroll
      for (int q = 0; q < 8; ++q) { b[q] = 0.f; c[q] = 0.f; d[q] = 0.f; }
    }
    for (; e + 3 < e1; e += 4) {
      int s0 = es[e], s1 = es[e + 1], s2 = es[e + 2], s3 = es[e + 3];
      uint4 u0 = in4[(size_t)s0 * 5 + pos];
      uint4 u1 = in4[(size_t)s1 * 5 + pos];
      uint4 u2 = in4[(size_t)s2 * 5 + pos];
      uint4 u3 = in4[(size_t)s3 * 5 + pos];
      ACC8(u0, a);
      ACC8(u1, b);
      ACC8(u2, c);
      ACC8(u3, d);
    }
    for (; e < e1; ++e) {
      uint4 uu = in4[(size_t)es[e] * 5 + pos];
      ACC8(uu, a);
    }
    float* r = &srow[w * 12 + g][pos * 8];
#pragma unroll
    for (int q = 0; q < 8; ++q) r[q] = a[q] + b[q] + c[q] + d[q];
  }
  __syncthreads();

  if (OUT_HALF) {
    for (int i = tid; i < 48 * 20; i += 256) {
      int l = i / 20, jj = i - l * 20;
      int vv = blockIdx.x * 48 + l;
      if (vv < n) {
        float dv = dinv[vv];
        const float* row = srow[l];
        float s0 = 0.f, s1 = 0.f;
#pragma unroll
        for (int k = 0; k < DD; ++k) {
          s0 = fmaf(row[k], sWT[k * DD + 2 * jj], s0);
          s1 = fmaf(row[k], sWT[k * DD + 2 * jj + 1], s1);
        }
        s0 = fmaf(s0, dv, sb[2 * jj]);
        s1 = fmaf(s1, dv, sb[2 * jj + 1]);
        s0 = fmaxf(s0, 0.f) * dv;  // relu + next-layer prescale
        s1 = fmaxf(s1, 0.f) * dv;
        outh[(size_t)vv * 20 + jj] = __float22half2_rn(make_float2(s0, s1));
      }
    }
  } else {
    for (int i = tid; i < 48 * DD; i += 256) {
      int l = i / DD, j = i - l * DD;
      int vv = blockIdx.x * 48 + l;
      if (vv < n) {
        float dv = dinv[vv];
        const float* row = srow[l];
        float acc = 0.f;
#pragma unroll
        for (int k = 0; k < DD; ++k) acc = fmaf(row[k], sWT[k * DD + j], acc);
        outf[(size_t)vv * DD + j] = fmaf(acc, dv, sb[j]);
      }
    }
  }
#undef ACC8
}

extern "C" void kernel_launch(void* const* d_in, const int* in_sizes, int n_in,
                              void* d_out, int out_size, void* d_ws, size_t ws_size,
                              hipStream_t stream) {
  const float* x = (const float*)d_in[0];
  const int* ei = (const int*)d_in[1];
  const float* W1 = (const float*)d_in[2];
  const float* b1 = (const float*)d_in[3];
  const float* W2 = (const float*)d_in[4];
  const float* b2 = (const float*)d_in[5];

  const int n = in_sizes[0] / DD;  // 100000
  const int E = in_sizes[1] / 2;   // 1600000
  const int* src = ei;
  const int* dst = ei + E;
  const int n4 = n * (DD / 4);
  const int nsb = (n + SCAN_B - 1) / SCAN_B;
  const int PS = (n + 7) / 8;                 // 12500 (local id < 2^14, src < 2^17)
  const unsigned M = (unsigned)((((unsigned long long)1 << 31) + PS - 1) / PS);
  const int CAP = E / 8 + 16384;              // per-bin capacity (massive slack)
  const int NCH = (E + 256 * PITER - 1) / (256 * PITER);

  float* out = (float*)d_out;

  // ws (~23.6 MB): dinv | ideg | gcur | cursor | bsum | ebin∪hs | es | xs
  char* w = (char*)d_ws;
  float* dinv = (float*)w;       w += (size_t)n * 4;
  int* ideg = (int*)w;           w += (size_t)n * 4;
  int* gcur = (int*)w;           w += 64;                      // 8 bin cursors (+pad)
  int* cursor = (int*)w;         w += (size_t)n * 4;
  int* bsum = (int*)w;           w += (size_t)SCAN_B * 4;
  char* ebin_hs = w;             w += (size_t)n * DD * 2;      // max(ebin 6.92MB, hs 8MB)
  int* es = (int*)w;             w += (size_t)E * 4;
  uint2* xs8 = (uint2*)w;        w += (size_t)n * DD * 2;

  unsigned* ebin = (unsigned*)ebin_hs;
  uint2* hs8 = (uint2*)ebin_hs;  // live only after sortB consumed ebin

  // zero ideg AND gcur (contiguous)
  hipMemsetAsync(ideg, 0, (size_t)n * 4 + 64, stream);

  k_binA<<<NCH, 256, 0, stream>>>(src, dst, gcur, ebin, E, PS, M, CAP);
  k_countB<<<NBPB * 8, 256, 0, stream>>>(ebin, gcur, ideg, PS, CAP);
  k_prescale<<<(n4 + 255) / 256, 256, 0, stream>>>((const float4*)x, ideg, dinv, xs8, n4, n);

  k_scan1<<<nsb, SCAN_B, 0, stream>>>(ideg, cursor, bsum, n);
  k_scan2<<<1, SCAN_B, 0, stream>>>(bsum, nsb);
  k_scan3<<<(n + 255) / 256, 256, 0, stream>>>(cursor, bsum, n);
  k_sortB<<<NBPB * 8, 256, 0, stream>>>(ebin, gcur, cursor, es, PS, CAP);

  const int NBK = (n + 47) / 48;
  k_layer<1><<<NBK, 256, 0, stream>>>((const uint4*)xs8, es, ideg, cursor, dinv, W1, b1,
                                      nullptr, (__half2*)hs8, n);
  k_layer<0><<<NBK, 256, 0, stream>>>((const uint4*)hs8, es, ideg, cursor, dinv, W2, b2,
                                      out, nullptr, n);
}

// Round 8
// 157.943 us; speedup vs baseline: 1.7598x; 1.7598x over previous
//
#include <hip/hip_runtime.h>
#include <hip/hip_fp16.h>

#define DD 40
#define PITER 32   // edges per thread in pass A (chunk = 256*PITER = 8192)
#define NP 512     // dst partitions; one pass-B block owns one partition

// ---------- Pass A: bin edges by dst-partition (512 bins) ----------
// LDS histogram -> ONE global atomicAdd per bin per block (~100K total, not 1.6M),
// then dense scatter of packed (local<<17)|src into the reserved window.
__global__ void k_binA(const int* __restrict__ src, const int* __restrict__ dst,
                       int* __restrict__ gcur, unsigned* __restrict__ ebin,
                       int E, int PS, unsigned M, int CAPB) {
  __shared__ int hist[NP];
  __shared__ int curs[NP];
  const int tid = threadIdx.x;
  hist[tid] = 0;
  hist[tid + 256] = 0;
  __syncthreads();
  const int base = blockIdx.x * (256 * PITER);
  for (int it = 0; it < PITER; ++it) {
    int i = base + it * 256 + tid;
    if (i < E) {
      unsigned t = (unsigned)dst[i];
      int b = (int)(((unsigned long long)t * M) >> 31);
      atomicAdd(&hist[b], 1);
    }
  }
  __syncthreads();
#pragma unroll
  for (int q = 0; q < 2; ++q) {
    int b = tid + q * 256;
    int h = hist[b];
    int old = h ? atomicAdd(&gcur[b], h) : 0;
    curs[b] = b * CAPB + old;
  }
  __syncthreads();
  for (int it = 0; it < PITER; ++it) {
    int i = base + it * 256 + tid;
    if (i < E) {
      unsigned t = (unsigned)dst[i];
      int b = (int)(((unsigned long long)t * M) >> 31);
      unsigned local = t - (unsigned)(b * PS);
      int pos = atomicAdd(&curs[b], 1);
      ebin[pos] = (local << 17) | (unsigned)src[i];
    }
  }
}

// ---------- Pass B: one block per partition. LDS degree count + LDS scan +
// LDS-cursor counting sort. Zero per-edge global atomics. Also emits dinv. ----------
__global__ __launch_bounds__(256) void k_partB(
    const unsigned* __restrict__ ebin, const int* __restrict__ gcur,
    int* __restrict__ ideg, int* __restrict__ cursor, float* __restrict__ dinv,
    int* __restrict__ es, int PS, int CAPB, int CAPE, int n) {
  __shared__ int sdeg[256];
  __shared__ int sbuf[2][256];
  __shared__ int scur[256];
  const int p = blockIdx.x;
  const int tid = threadIdx.x;
  const int start = p * CAPB;
  const int cnt = gcur[p];

  sdeg[tid] = 0;
  __syncthreads();
  for (int i = tid; i < cnt; i += 256) atomicAdd(&sdeg[ebin[start + i] >> 17], 1);
  __syncthreads();

  // inclusive scan of sdeg (256 elements, Hillis-Steele)
  int v = sdeg[tid];
  sbuf[0][tid] = v;
  __syncthreads();
  int pi = 0;
  for (int off = 1; off < 256; off <<= 1) {
    int x = sbuf[pi][tid];
    if (tid >= off) x += sbuf[pi][tid - off];
    sbuf[pi ^ 1][tid] = x;
    __syncthreads();
    pi ^= 1;
  }
  int incl = sbuf[pi][tid];
  scur[tid] = incl - v;  // exclusive prefix = running cursor

  const int node = p * PS + tid;
  if (tid < PS && node < n) {
    ideg[node] = v;
    cursor[node] = p * CAPE + incl;       // row END in es coords
    dinv[node] = rsqrtf((float)(v + 1));  // +1 self-loop
  }
  __syncthreads();

  for (int i = tid; i < cnt; i += 256) {
    unsigned pk = ebin[start + i];
    int l = (int)(pk >> 17);
    int pos = atomicAdd(&scur[l], 1);  // LDS atomic
    es[p * CAPE + pos] = (int)(pk & 0x1FFFFu);
  }
}

// xs = fp16(dinv*x) (80B rows)
__global__ void k_prescale(const float4* __restrict__ x4, const float* __restrict__ dinv,
                           uint2* __restrict__ xs8, int n4) {
  int i = blockIdx.x * blockDim.x + threadIdx.x;
  if (i < n4) {
    float w = dinv[i / 10];
    float4 v = x4[i];
    __half2 ha = __float22half2_rn(make_float2(v.x * w, v.y * w));
    __half2 hb = __float22half2_rn(make_float2(v.z * w, v.w * w));
    uint2 u;
    u.x = *(unsigned*)&ha;
    u.y = *(unsigned*)&hb;
    xs8[i] = u;
  }
}

// ---------- Gather + fused linear. 12 nodes/wave, 5 lanes x uint4(8 fp16)/node,
// 4-way unroll -> 48 gathers in flight per wave. ----------
template <int OUT_HALF>
__global__ __launch_bounds__(256) void k_layer(
    const uint4* __restrict__ in4, const int* __restrict__ es,
    const int* __restrict__ ideg, const int* __restrict__ cursor,
    const float* __restrict__ dinv, const float* __restrict__ W,
    const float* __restrict__ bias, float* __restrict__ outf,
    __half2* __restrict__ outh, int n) {
  __shared__ float sWT[DD * DD];  // sWT[k*40+j] = W[j*40+k]
  __shared__ float sb[DD];
  __shared__ float srow[48][DD];
  const int tid = threadIdx.x;
  for (int t = tid; t < DD * DD; t += 256) sWT[(t % DD) * DD + t / DD] = W[t];
  if (tid < DD) sb[tid] = bias[tid];

  const int w = tid >> 6, lane = tid & 63;
  const int g = lane / 5, pos = lane - g * 5;  // g==12 (lanes 60-63) idle
  const int v = blockIdx.x * 48 + w * 12 + g;

#define ACC8(U, A)                                   \
  {                                                  \
    const __half2* hh = (const __half2*)&(U);        \
    float2 f0 = __half22float2(hh[0]);               \
    float2 f1 = __half22float2(hh[1]);               \
    float2 f2 = __half22float2(hh[2]);               \
    float2 f3 = __half22float2(hh[3]);               \
    A[0] += f0.x; A[1] += f0.y; A[2] += f1.x;        \
    A[3] += f1.y; A[4] += f2.x; A[5] += f2.y;        \
    A[6] += f3.x; A[7] += f3.y;                      \
  }

  if (g < 12 && v < n) {
    const int e1 = cursor[v];  // row end
    int e = e1 - ideg[v];      // row start
    float a[8], b[8], c[8], d[8];
    {
      uint4 u = in4[(size_t)v * 5 + pos];  // self-loop term
      const __half2* hh = (const __half2*)&u;
      float2 f0 = __half22float2(hh[0]);
      float2 f1 = __half22float2(hh[1]);
      float2 f2 = __half22float2(hh[2]);
      float2 f3 = __half22float2(hh[3]);
      a[0] = f0.x; a[1] = f0.y; a[2] = f1.x; a[3] = f1.y;
      a[4] = f2.x; a[5] = f2.y; a[6] = f3.x; a[7] = f3.y;
#pragma unroll
      for (int q = 0; q < 8; ++q) { b[q] = 0.f; c[q] = 0.f; d[q] = 0.f; }
    }
    for (; e + 3 < e1; e += 4) {
      int s0 = es[e], s1 = es[e + 1], s2 = es[e + 2], s3 = es[e + 3];
      uint4 u0 = in4[(size_t)s0 * 5 + pos];
      uint4 u1 = in4[(size_t)s1 * 5 + pos];
      uint4 u2 = in4[(size_t)s2 * 5 + pos];
      uint4 u3 = in4[(size_t)s3 * 5 + pos];
      ACC8(u0, a);
      ACC8(u1, b);
      ACC8(u2, c);
      ACC8(u3, d);
    }
    for (; e < e1; ++e) {
      uint4 uu = in4[(size_t)es[e] * 5 + pos];
      ACC8(uu, a);
    }
    float* r = &srow[w * 12 + g][pos * 8];
#pragma unroll
    for (int q = 0; q < 8; ++q) r[q] = a[q] + b[q] + c[q] + d[q];
  }
  __syncthreads();

  if (OUT_HALF) {
    for (int i = tid; i < 48 * 20; i += 256) {
      int l = i / 20, jj = i - l * 20;
      int vv = blockIdx.x * 48 + l;
      if (vv < n) {
        float dv = dinv[vv];
        const float* row = srow[l];
        float s0 = 0.f, s1 = 0.f;
#pragma unroll
        for (int k = 0; k < DD; ++k) {
          s0 = fmaf(row[k], sWT[k * DD + 2 * jj], s0);
          s1 = fmaf(row[k], sWT[k * DD + 2 * jj + 1], s1);
        }
        s0 = fmaf(s0, dv, sb[2 * jj]);
        s1 = fmaf(s1, dv, sb[2 * jj + 1]);
        s0 = fmaxf(s0, 0.f) * dv;  // relu + next-layer prescale
        s1 = fmaxf(s1, 0.f) * dv;
        outh[(size_t)vv * 20 + jj] = __float22half2_rn(make_float2(s0, s1));
      }
    }
  } else {
    for (int i = tid; i < 48 * DD; i += 256) {
      int l = i / DD, j = i - l * DD;
      int vv = blockIdx.x * 48 + l;
      if (vv < n) {
        float dv = dinv[vv];
        const float* row = srow[l];
        float acc = 0.f;
#pragma unroll
        for (int k = 0; k < DD; ++k) acc = fmaf(row[k], sWT[k * DD + j], acc);
        outf[(size_t)vv * DD + j] = fmaf(acc, dv, sb[j]);
      }
    }
  }
#undef ACC8
}

extern "C" void kernel_launch(void* const* d_in, const int* in_sizes, int n_in,
                              void* d_out, int out_size, void* d_ws, size_t ws_size,
                              hipStream_t stream) {
  const float* x = (const float*)d_in[0];
  const int* ei = (const int*)d_in[1];
  const float* W1 = (const float*)d_in[2];
  const float* b1 = (const float*)d_in[3];
  const float* W2 = (const float*)d_in[4];
  const float* b2 = (const float*)d_in[5];

  const int n = in_sizes[0] / DD;  // 100000
  const int E = in_sizes[1] / 2;   // 1600000
  const int* src = ei;
  const int* dst = ei + E;
  const int n4 = n * (DD / 4);
  const int PS = (n + NP - 1) / NP;  // 196 local nodes/partition (<256, fits 15-bit pack)
  const unsigned M = (unsigned)((((unsigned long long)1 << 31) + PS - 1) / PS);
  const int CAPB = E / NP + 512;     // per-bin window (mean 3125, sigma~56 -> 9 sigma slack)
  const int CAPE = CAPB;             // per-partition es window
  const int NCH = (E + 256 * PITER - 1) / (256 * PITER);

  float* out = (float*)d_out;

  // ws (~24.8 MB): dinv | ideg | cursor | gcur | ebin(∪hs) | es | xs
  char* w = (char*)d_ws;
  float* dinv = (float*)w;   w += (size_t)n * 4;
  int* ideg = (int*)w;       w += (size_t)n * 4;
  int* cursor = (int*)w;     w += (size_t)n * 4;
  int* gcur = (int*)w;       w += (size_t)NP * 4;
  char* ebin_hs = w;         w += (size_t)n * DD * 2;     // max(ebin 7.45MB, hs 8MB)
  int* es = (int*)w;         w += (size_t)NP * CAPE * 4;  // 7.45MB
  uint2* xs8 = (uint2*)w;    w += (size_t)n * DD * 2;

  unsigned* ebin = (unsigned*)ebin_hs;
  uint2* hs8 = (uint2*)ebin_hs;  // live only after k_partB consumed ebin

  hipMemsetAsync(gcur, 0, (size_t)NP * 4, stream);

  k_binA<<<NCH, 256, 0, stream>>>(src, dst, gcur, ebin, E, PS, M, CAPB);
  k_partB<<<NP, 256, 0, stream>>>(ebin, gcur, ideg, cursor, dinv, es, PS, CAPB, CAPE, n);
  k_prescale<<<(n4 + 255) / 256, 256, 0, stream>>>((const float4*)x, dinv, xs8, n4);

  const int NBK = (n + 47) / 48;
  k_layer<1><<<NBK, 256, 0, stream>>>((const uint4*)xs8, es, ideg, cursor, dinv, W1, b1,
                                      nullptr, (__half2*)hs8, n);
  k_layer<0><<<NBK, 256, 0, stream>>>((const uint4*)hs8, es, ideg, cursor, dinv, W2, b2,
                                      out, nullptr, n);
}

// Round 9
// 151.814 us; speedup vs baseline: 1.8308x; 1.0404x over previous
//
#include <hip/hip_runtime.h>
#include <hip/hip_fp16.h>

#define DD 40
#define PITER 32   // edges per thread in pass A (chunk = 256*PITER = 8192)
#define NP 512     // dst partitions; one pass-B block owns one partition
#define SROW_LD 44 // padded LDS row stride (11 x 16B: b128-aligned, kills bank conflicts)

// ---------- Pass A: bin edges by dst-partition (512 bins) ----------
__global__ void k_binA(const int* __restrict__ src, const int* __restrict__ dst,
                       int* __restrict__ gcur, unsigned* __restrict__ ebin,
                       int E, int PS, unsigned M, int CAPB) {
  __shared__ int hist[NP];
  __shared__ int curs[NP];
  const int tid = threadIdx.x;
  hist[tid] = 0;
  hist[tid + 256] = 0;
  __syncthreads();
  const int base = blockIdx.x * (256 * PITER);
  for (int it = 0; it < PITER; ++it) {
    int i = base + it * 256 + tid;
    if (i < E) {
      unsigned t = (unsigned)dst[i];
      int b = (int)(((unsigned long long)t * M) >> 31);
      atomicAdd(&hist[b], 1);
    }
  }
  __syncthreads();
#pragma unroll
  for (int q = 0; q < 2; ++q) {
    int b = tid + q * 256;
    int h = hist[b];
    int old = h ? atomicAdd(&gcur[b], h) : 0;
    curs[b] = b * CAPB + old;
  }
  __syncthreads();
  for (int it = 0; it < PITER; ++it) {
    int i = base + it * 256 + tid;
    if (i < E) {
      unsigned t = (unsigned)dst[i];
      int b = (int)(((unsigned long long)t * M) >> 31);
      unsigned local = t - (unsigned)(b * PS);
      int pos = atomicAdd(&curs[b], 1);
      ebin[pos] = (local << 17) | (unsigned)src[i];
    }
  }
}

// ---------- Pass B: one block per partition; LDS count/scan/sort; emits dinv ----------
__global__ __launch_bounds__(256) void k_partB(
    const unsigned* __restrict__ ebin, const int* __restrict__ gcur,
    int* __restrict__ ideg, int* __restrict__ cursor, float* __restrict__ dinv,
    int* __restrict__ es, int PS, int CAPB, int CAPE, int n) {
  __shared__ int sdeg[256];
  __shared__ int sbuf[2][256];
  __shared__ int scur[256];
  const int p = blockIdx.x;
  const int tid = threadIdx.x;
  const int start = p * CAPB;
  const int cnt = gcur[p];

  sdeg[tid] = 0;
  __syncthreads();
  for (int i = tid; i < cnt; i += 256) atomicAdd(&sdeg[ebin[start + i] >> 17], 1);
  __syncthreads();

  int v = sdeg[tid];
  sbuf[0][tid] = v;
  __syncthreads();
  int pi = 0;
  for (int off = 1; off < 256; off <<= 1) {
    int x = sbuf[pi][tid];
    if (tid >= off) x += sbuf[pi][tid - off];
    sbuf[pi ^ 1][tid] = x;
    __syncthreads();
    pi ^= 1;
  }
  int incl = sbuf[pi][tid];
  scur[tid] = incl - v;

  const int node = p * PS + tid;
  if (tid < PS && node < n) {
    ideg[node] = v;
    cursor[node] = p * CAPE + incl;       // row END in es coords
    dinv[node] = rsqrtf((float)(v + 1));  // +1 self-loop
  }
  __syncthreads();

  for (int i = tid; i < cnt; i += 256) {
    unsigned pk = ebin[start + i];
    int l = (int)(pk >> 17);
    int pos = atomicAdd(&scur[l], 1);  // LDS atomic
    es[p * CAPE + pos] = (int)(pk & 0x1FFFFu);
  }
}

// xs = fp16(dinv*x) (80B rows)
__global__ void k_prescale(const float4* __restrict__ x4, const float* __restrict__ dinv,
                           uint2* __restrict__ xs8, int n4) {
  int i = blockIdx.x * blockDim.x + threadIdx.x;
  if (i < n4) {
    float w = dinv[i / 10];
    float4 v = x4[i];
    __half2 ha = __float22half2_rn(make_float2(v.x * w, v.y * w));
    __half2 hb = __float22half2_rn(make_float2(v.z * w, v.w * w));
    uint2 u;
    u.x = *(unsigned*)&ha;
    u.y = *(unsigned*)&hb;
    xs8[i] = u;
  }
}

// ---------- Gather + fused linear. 12 nodes/wave, 5 lanes x uint4(8 fp16)/node.
// 8-deep load unroll (2 acc sets) -> 8 outstanding gathers/lane. ----------
template <int OUT_HALF>
__global__ __launch_bounds__(256) void k_layer(
    const uint4* __restrict__ in4, const int* __restrict__ es,
    const int* __restrict__ ideg, const int* __restrict__ cursor,
    const float* __restrict__ dinv, const float* __restrict__ W,
    const float* __restrict__ bias, float* __restrict__ outf,
    __half2* __restrict__ outh, int n) {
  __shared__ float sWT[DD * DD];  // sWT[k*40+j] = W[j*40+k]
  __shared__ float sb[DD];
  __shared__ float srow[48][SROW_LD];
  const int tid = threadIdx.x;

  const int w = tid >> 6, lane = tid & 63;
  const int g = lane / 5, pos = lane - g * 5;  // g==12 (lanes 60-63) idle
  const int v = blockIdx.x * 48 + w * 12 + g;

#define ACC8(U, A)                                   \
  {                                                  \
    const __half2* hh = (const __half2*)&(U);        \
    float2 f0 = __half22float2(hh[0]);               \
    float2 f1 = __half22float2(hh[1]);               \
    float2 f2 = __half22float2(hh[2]);               \
    float2 f3 = __half22float2(hh[3]);               \
    A[0] += f0.x; A[1] += f0.y; A[2] += f1.x;        \
    A[3] += f1.y; A[4] += f2.x; A[5] += f2.y;        \
    A[6] += f3.x; A[7] += f3.y;                      \
  }

  if (g < 12 && v < n) {
    const int e1 = cursor[v];  // row end
    int e = e1 - ideg[v];      // row start
    float a[8], b[8];
    {
      uint4 u = in4[(size_t)v * 5 + pos];  // self-loop term
      const __half2* hh = (const __half2*)&u;
      float2 f0 = __half22float2(hh[0]);
      float2 f1 = __half22float2(hh[1]);
      float2 f2 = __half22float2(hh[2]);
      float2 f3 = __half22float2(hh[3]);
      a[0] = f0.x; a[1] = f0.y; a[2] = f1.x; a[3] = f1.y;
      a[4] = f2.x; a[5] = f2.y; a[6] = f3.x; a[7] = f3.y;
#pragma unroll
      for (int q = 0; q < 8; ++q) b[q] = 0.f;
    }
    // 8-deep: issue all 8 loads before any consume
    for (; e + 7 < e1; e += 8) {
      int s0 = es[e],     s1 = es[e + 1], s2 = es[e + 2], s3 = es[e + 3];
      int s4 = es[e + 4], s5 = es[e + 5], s6 = es[e + 6], s7 = es[e + 7];
      uint4 u0 = in4[(size_t)s0 * 5 + pos];
      uint4 u1 = in4[(size_t)s1 * 5 + pos];
      uint4 u2 = in4[(size_t)s2 * 5 + pos];
      uint4 u3 = in4[(size_t)s3 * 5 + pos];
      uint4 u4 = in4[(size_t)s4 * 5 + pos];
      uint4 u5 = in4[(size_t)s5 * 5 + pos];
      uint4 u6 = in4[(size_t)s6 * 5 + pos];
      uint4 u7 = in4[(size_t)s7 * 5 + pos];
      ACC8(u0, a); ACC8(u1, b); ACC8(u2, a); ACC8(u3, b);
      ACC8(u4, a); ACC8(u5, b); ACC8(u6, a); ACC8(u7, b);
    }
    for (; e + 3 < e1; e += 4) {
      int s0 = es[e], s1 = es[e + 1], s2 = es[e + 2], s3 = es[e + 3];
      uint4 u0 = in4[(size_t)s0 * 5 + pos];
      uint4 u1 = in4[(size_t)s1 * 5 + pos];
      uint4 u2 = in4[(size_t)s2 * 5 + pos];
      uint4 u3 = in4[(size_t)s3 * 5 + pos];
      ACC8(u0, a); ACC8(u1, b); ACC8(u2, a); ACC8(u3, b);
    }
    for (; e < e1; ++e) {
      uint4 uu = in4[(size_t)es[e] * 5 + pos];
      ACC8(uu, a);
    }
    float* r = &srow[w * 12 + g][pos * 8];
#pragma unroll
    for (int q = 0; q < 8; ++q) r[q] = a[q] + b[q];
  }

  // Stage W/bias AFTER gather so wave's first instructions are the gathers.
  for (int t = tid; t < DD * DD; t += 256) sWT[(t % DD) * DD + t / DD] = W[t];
  if (tid < DD) sb[tid] = bias[tid];
  __syncthreads();

  if (OUT_HALF) {
    for (int i = tid; i < 48 * 20; i += 256) {
      int l = i / 20, jj = i - l * 20;
      int vv = blockIdx.x * 48 + l;
      if (vv < n) {
        float dv = dinv[vv];
        const float* row = srow[l];
        float s0 = 0.f, s1 = 0.f;
#pragma unroll
        for (int k = 0; k < DD; ++k) {
          s0 = fmaf(row[k], sWT[k * DD + 2 * jj], s0);
          s1 = fmaf(row[k], sWT[k * DD + 2 * jj + 1], s1);
        }
        s0 = fmaf(s0, dv, sb[2 * jj]);
        s1 = fmaf(s1, dv, sb[2 * jj + 1]);
        s0 = fmaxf(s0, 0.f) * dv;  // relu + next-layer prescale
        s1 = fmaxf(s1, 0.f) * dv;
        outh[(size_t)vv * 20 + jj] = __float22half2_rn(make_float2(s0, s1));
      }
    }
  } else {
    for (int i = tid; i < 48 * DD; i += 256) {
      int l = i / DD, j = i - l * DD;
      int vv = blockIdx.x * 48 + l;
      if (vv < n) {
        float dv = dinv[vv];
        const float* row = srow[l];
        float acc = 0.f;
#pragma unroll
        for (int k = 0; k < DD; ++k) acc = fmaf(row[k], sWT[k * DD + j], acc);
        outf[(size_t)vv * DD + j] = fmaf(acc, dv, sb[j]);
      }
    }
  }
#undef ACC8
}

extern "C" void kernel_launch(void* const* d_in, const int* in_sizes, int n_in,
                              void* d_out, int out_size, void* d_ws, size_t ws_size,
                              hipStream_t stream) {
  const float* x = (const float*)d_in[0];
  const int* ei = (const int*)d_in[1];
  const float* W1 = (const float*)d_in[2];
  const float* b1 = (const float*)d_in[3];
  const float* W2 = (const float*)d_in[4];
  const float* b2 = (const float*)d_in[5];

  const int n = in_sizes[0] / DD;  // 100000
  const int E = in_sizes[1] / 2;   // 1600000
  const int* src = ei;
  const int* dst = ei + E;
  const int n4 = n * (DD / 4);
  const int PS = (n + NP - 1) / NP;  // 196 local nodes/partition
  const unsigned M = (unsigned)((((unsigned long long)1 << 31) + PS - 1) / PS);
  const int CAPB = E / NP + 512;
  const int CAPE = CAPB;
  const int NCH = (E + 256 * PITER - 1) / (256 * PITER);

  float* out = (float*)d_out;

  // ws (~24.8 MB): dinv | ideg | cursor | gcur | ebin(∪hs) | es | xs
  char* w = (char*)d_ws;
  float* dinv = (float*)w;   w += (size_t)n * 4;
  int* ideg = (int*)w;       w += (size_t)n * 4;
  int* cursor = (int*)w;     w += (size_t)n * 4;
  int* gcur = (int*)w;       w += (size_t)NP * 4;
  char* ebin_hs = w;         w += (size_t)n * DD * 2;
  int* es = (int*)w;         w += (size_t)NP * CAPE * 4;
  uint2* xs8 = (uint2*)w;    w += (size_t)n * DD * 2;

  unsigned* ebin = (unsigned*)ebin_hs;
  uint2* hs8 = (uint2*)ebin_hs;  // live only after k_partB consumed ebin

  hipMemsetAsync(gcur, 0, (size_t)NP * 4, stream);

  k_binA<<<NCH, 256, 0, stream>>>(src, dst, gcur, ebin, E, PS, M, CAPB);
  k_partB<<<NP, 256, 0, stream>>>(ebin, gcur, ideg, cursor, dinv, es, PS, CAPB, CAPE, n);
  k_prescale<<<(n4 + 255) / 256, 256, 0, stream>>>((const float4*)x, dinv, xs8, n4);

  const int NBK = (n + 47) / 48;
  k_layer<1><<<NBK, 256, 0, stream>>>((const uint4*)xs8, es, ideg, cursor, dinv, W1, b1,
                                      nullptr, (__half2*)hs8, n);
  k_layer<0><<<NBK, 256, 0, stream>>>((const uint4*)hs8, es, ideg, cursor, dinv, W2, b2,
                                      out, nullptr, n);
}